// Round 5
// baseline (342.621 us; speedup 1.0000x reference)
//
#include <hip/hip_runtime.h>
#include <math.h>

#define NZ    128
#define H1    512
#define H2    1024
#define IMG   784
#define IMGP3 896     // layer-3 N padded to 7*128
#define BATCH 4096
#define NGEN  10
#define MPAD  128     // packed-row slack so tail m-blocks can stage past ng

typedef _Float16 f16;
typedef __attribute__((ext_vector_type(8))) _Float16 half8;
typedef __attribute__((ext_vector_type(4))) float floatx4;

__device__ __forceinline__ void cp16(void* l, const void* g) {
    __builtin_amdgcn_global_load_lds((const __attribute__((address_space(1))) void*)g,
                                     (__attribute__((address_space(3))) void*)l, 16, 0, 0);
}

// ---------------- bucket samples by generator ----------------
__global__ void bucket_kernel(const int* __restrict__ g_idx,
                              int* __restrict__ counts,
                              int* __restrict__ lists) {
    int b = blockIdx.x * blockDim.x + threadIdx.x;
    if (b < BATCH) {
        int g = g_idx[b];
        int pos = atomicAdd(&counts[g], 1);
        lists[g * BATCH + pos] = b;
    }
}

// ---------------- perm: packed row -> sample id ----------------
__global__ void build_perm(const int* __restrict__ counts, const int* __restrict__ lists,
                           int* __restrict__ perm) {
    const int g = blockIdx.x;
    int start = 0;
    for (int i = 0; i < g; ++i) start += counts[i];
    const int ng = counts[g];
    for (int i = threadIdx.x; i < ng; i += 256)
        perm[start + i] = lists[g * BATCH + i];
}

// ---------------- pack + convert z: zp[r][:] = f16(z[perm[r]][:]) ----------------
__global__ void pack_z(const float* __restrict__ z, const int* __restrict__ perm,
                       f16* __restrict__ zp) {
    const int i = blockIdx.x * 256 + threadIdx.x;   // BATCH * (NZ/4)
    const int r = i >> 5, c = (i & 31) * 4;
    const int s = perm[r];
    float4 v = *(const float4*)(z + (size_t)s * NZ + c);
    union { ushort4 u; f16 h[4]; } o;
    o.h[0] = (f16)v.x; o.h[1] = (f16)v.y; o.h[2] = (f16)v.z; o.h[3] = (f16)v.w;
    *(ushort4*)(zp + (size_t)r * NZ + c) = o.u;
}

// ---------------- transpose W: [g][K][N] f32 -> [g][NPAD][K] f16 ----------------
template<int K, int N, int NPAD>
__global__ __launch_bounds__(256)
void transpose_f16(const float* __restrict__ W, f16* __restrict__ Wt) {
    const int g  = blockIdx.z;
    const int k0 = blockIdx.x * 32;
    const int n0 = blockIdx.y * 32;
    __shared__ f16 L[32][36];
    const int t = threadIdx.x;
    {
        const int kk = t >> 3;
        const int nq = (t & 7) * 4;
        float4 v = make_float4(0.f, 0.f, 0.f, 0.f);
        if (n0 + nq < N)   // N % 4 == 0: quads never straddle
            v = *(const float4*)(W + ((size_t)g * K + (k0 + kk)) * N + n0 + nq);
        L[nq + 0][kk] = (f16)v.x;
        L[nq + 1][kk] = (f16)v.y;
        L[nq + 2][kk] = (f16)v.z;
        L[nq + 3][kk] = (f16)v.w;
    }
    __syncthreads();
    {
        const int nn = t >> 3;
        const int kq = (t & 7) * 4;
        *(ushort4*)(Wt + ((size_t)g * NPAD + (n0 + nn)) * K + k0 + kq) =
            *(const ushort4*)&L[nn][kq];
    }
}

// ---------------- m97-style 128x128 grouped GEMM on packed rows ----------------
// Block = (m-block within gen segment, 128-col n-tile, gen). Single-buffer LDS,
// global_load_lds width 16 for both A and B. LDS stores a XOR-swizzled layout
// (k-quad ^ ((row>>1)&3)) so frag ds_read_b128s are 2-way max (free).
// 4 waves in 2x2; each wave 64x64 = 4x4 frags of 16x16x32 f16 MFMA.
// ACT: 0 relu, 1 tanh. SCATTER: 0 -> packed f16 Cp, 1 -> f32 out via perm.
template<int K, int NOUT, int NPADB, int ACT, int SCATTER>
__global__ __launch_bounds__(256)
void gemm128(const f16* __restrict__ Ap, const f16* __restrict__ Wt,
             const float* __restrict__ bias, f16* __restrict__ Cp,
             float* __restrict__ Cout, const int* __restrict__ counts,
             const int* __restrict__ perm) {
    const int g  = blockIdx.z;
    const int ng = counts[g];
    const int m0 = blockIdx.x * 128;
    if (m0 >= ng) return;                 // block-uniform early exit
    int seg0 = 0;
    for (int i = 0; i < g; ++i) seg0 += counts[i];
    const int n0 = blockIdx.y * 128;

    __shared__ f16 As[128 * 32];
    __shared__ f16 Bs[128 * 32];

    const int tid = threadIdx.x, lane = tid & 63, w = tid >> 6;

    // staging: group grp = w*2+j covers tile rows [grp*16, +16); lane l owns
    // LDS slot grp*1KB + l*16B = (row = grp*16 + (l>>2), swizzled quad l&3),
    // fetching global k-quad (l&3) ^ ((row>>1)&3).
    const int sr = lane >> 2;
    const int sq = ((lane & 3) ^ ((sr >> 1) & 3)) * 8;
    const f16* gA[2]; const f16* gB[2]; f16* lA[2]; f16* lB[2];
    #pragma unroll
    for (int j = 0; j < 2; ++j) {
        const int grp = w * 2 + j;
        gA[j] = Ap + (size_t)(seg0 + m0 + grp * 16 + sr) * K + sq;
        gB[j] = Wt + ((size_t)g * NPADB + n0 + grp * 16 + sr) * K + sq;
        lA[j] = As + grp * 512;
        lB[j] = Bs + grp * 512;
    }

    const int wm = (w & 1) * 64, wn = (w >> 1) * 64;
    const int lm = lane & 15, lq = lane >> 4;
    const int fq = (lq ^ ((lm >> 1) & 3)) * 8;  // swizzled quad for frag reads

    floatx4 acc[4][4] = {};

    for (int kc = 0; kc < K / 32; ++kc) {
        __syncthreads();                         // LDS safe to overwrite
        #pragma unroll
        for (int j = 0; j < 2; ++j) {
            cp16(lA[j], gA[j]); cp16(lB[j], gB[j]);
            gA[j] += 32; gB[j] += 32;
        }
        __syncthreads();                         // drain staging (vmcnt)
        half8 ah[4], bb[4];
        #pragma unroll
        for (int t = 0; t < 4; ++t) {
            ah[t] = *(const half8*)&As[(wm + t * 16 + lm) * 32 + fq];
            bb[t] = *(const half8*)&Bs[(wn + t * 16 + lm) * 32 + fq];
        }
        #pragma unroll
        for (int mt = 0; mt < 4; ++mt)
            #pragma unroll
            for (int nt = 0; nt < 4; ++nt)
                acc[mt][nt] = __builtin_amdgcn_mfma_f32_16x16x32_f16(
                    ah[mt], bb[nt], acc[mt][nt], 0, 0, 0);
    }

    // epilogue: C/D layout col = lane&15, row = (lane>>4)*4 + reg
    float bs[4];
    #pragma unroll
    for (int nt = 0; nt < 4; ++nt) {
        const int n = n0 + wn + nt * 16 + lm;
        bs[nt] = (n < NOUT) ? bias[(size_t)g * NOUT + n] : 0.f;
    }
    #pragma unroll
    for (int mt = 0; mt < 4; ++mt)
        #pragma unroll
        for (int rr = 0; rr < 4; ++rr) {
            const int row = m0 + wm + mt * 16 + lq * 4 + rr;
            if (row >= ng) continue;
            const size_t orow = SCATTER ? (size_t)perm[seg0 + row] : (size_t)(seg0 + row);
            #pragma unroll
            for (int nt = 0; nt < 4; ++nt) {
                const int n = n0 + wn + nt * 16 + lm;
                if (n >= NOUT) continue;
                float x = acc[mt][nt][rr] + bs[nt];
                if (ACT == 0) {
                    x = fmaxf(x, 0.f);
                } else {
                    const float e = __expf(2.f * x);   // tanh, inf-safe
                    x = 1.f - 2.f / (e + 1.f);
                }
                if (SCATTER) Cout[orow * NOUT + n] = x;
                else         Cp[orow * NOUT + n] = (f16)x;
            }
        }
}

extern "C" void kernel_launch(void* const* d_in, const int* in_sizes, int n_in,
                              void* d_out, int out_size, void* d_ws, size_t ws_size,
                              hipStream_t stream) {
    const float* z    = (const float*)d_in[0];
    const int*   gidx = (const int*)  d_in[1];
    const float* W1   = (const float*)d_in[2];
    const float* b1   = (const float*)d_in[3];
    const float* W2   = (const float*)d_in[4];
    const float* b2   = (const float*)d_in[5];
    const float* W3   = (const float*)d_in[6];
    const float* b3   = (const float*)d_in[7];
    float* out = (float*)d_out;

    char* ws = (char*)d_ws;
    size_t off = 0;
    auto alloc = [&](size_t bytes) { size_t o = off; off = (off + bytes + 255) & ~255ULL; return o; };
    int* counts = (int*)(ws + alloc(256));
    int* lists  = (int*)(ws + alloc((size_t)BATCH * NGEN * 4));
    int* perm   = (int*)(ws + alloc((size_t)(BATCH + MPAD) * 4));
    f16* zp  = (f16*)(ws + alloc((size_t)(BATCH + MPAD) * NZ * 2));
    f16* h1p = (f16*)(ws + alloc((size_t)(BATCH + MPAD) * H1 * 2));
    f16* h2p = (f16*)(ws + alloc((size_t)(BATCH + MPAD) * H2 * 2));
    f16* W1t = (f16*)(ws + alloc((size_t)NGEN * H1 * NZ * 2));
    f16* W2t = (f16*)(ws + alloc((size_t)NGEN * H2 * H1 * 2));
    f16* W3t = (f16*)(ws + alloc((size_t)NGEN * IMGP3 * H2 * 2));

    hipMemsetAsync(counts, 0, 256, stream);
    bucket_kernel<<<dim3(BATCH / 256), dim3(256), 0, stream>>>(gidx, counts, lists);
    build_perm<<<dim3(NGEN), dim3(256), 0, stream>>>(counts, lists, perm);
    pack_z<<<dim3(BATCH * (NZ / 4) / 256), dim3(256), 0, stream>>>(z, perm, zp);
    transpose_f16<NZ, H1, H1><<<dim3(NZ / 32, H1 / 32, NGEN), dim3(256), 0, stream>>>(W1, W1t);
    transpose_f16<H1, H2, H2><<<dim3(H1 / 32, H2 / 32, NGEN), dim3(256), 0, stream>>>(W2, W2t);
    transpose_f16<H2, IMG, IMGP3><<<dim3(H2 / 32, IMGP3 / 32, NGEN), dim3(256), 0, stream>>>(W3, W3t);

    // grids: x=32 covers any bucket size (empty m-blocks exit on counts[] read)
    gemm128<NZ, H1, H1, 0, 0><<<dim3(32, H1 / 128, NGEN), dim3(256), 0, stream>>>(
        zp, W1t, b1, h1p, nullptr, counts, perm);
    gemm128<H1, H2, H2, 0, 0><<<dim3(32, H2 / 128, NGEN), dim3(256), 0, stream>>>(
        h1p, W2t, b2, h2p, nullptr, counts, perm);
    gemm128<H2, IMG, IMGP3, 1, 1><<<dim3(32, IMGP3 / 128, NGEN), dim3(256), 0, stream>>>(
        h2p, W3t, b3, nullptr, out, counts, perm);
}

// Round 6
// 266.410 us; speedup vs baseline: 1.2861x; 1.2861x over previous
//
#include <hip/hip_runtime.h>
#include <math.h>

#define NZ    128
#define H1    512
#define H2    1024
#define IMG   784
#define IMGP  832     // layer-3 N padded to 26*32
#define BATCH 4096
#define NGEN  10
#define MPAD  128     // packed-row slack so tail supertiles can load past ng

typedef _Float16 f16;
typedef __attribute__((ext_vector_type(8))) _Float16 half8;
typedef __attribute__((ext_vector_type(4))) float floatx4;

// ---------------- histogram + segment starts + permutation (one block) ----------------
__global__ __launch_bounds__(1024)
void hist_perm(const int* __restrict__ g_idx, int* __restrict__ seg,
               int* __restrict__ perm) {
    __shared__ int lc[NGEN];
    __shared__ int lb[NGEN + 1];
    const int t = threadIdx.x;
    if (t < NGEN) lc[t] = 0;
    __syncthreads();
    int gv[BATCH / 1024];
    #pragma unroll
    for (int i = 0; i < BATCH / 1024; ++i) {
        gv[i] = g_idx[t + i * 1024];
        atomicAdd(&lc[gv[i]], 1);
    }
    __syncthreads();
    if (t == 0) {
        int s = 0;
        for (int g = 0; g < NGEN; ++g) { lb[g] = s; s += lc[g]; }
        lb[NGEN] = s;
    }
    __syncthreads();
    if (t <= NGEN) seg[t] = lb[t];
    if (t < NGEN) lc[t] = lb[t];          // reuse as cursors
    __syncthreads();
    #pragma unroll
    for (int i = 0; i < BATCH / 1024; ++i) {
        int p = atomicAdd(&lc[gv[i]], 1);
        perm[p] = t + i * 1024;
    }
}

// ---------------- pack + convert z: zp[r][:] = f16(z[perm[r]][:]) ----------------
__global__ void pack_z(const float* __restrict__ z, const int* __restrict__ perm,
                       f16* __restrict__ zp) {
    const int i = blockIdx.x * 256 + threadIdx.x;   // BATCH * (NZ/4)
    const int r = i >> 5, c = (i & 31) * 4;
    const int s = perm[r];
    float4 v = *(const float4*)(z + (size_t)s * NZ + c);
    union { ushort4 u; f16 h[4]; } o;
    o.h[0] = (f16)v.x; o.h[1] = (f16)v.y; o.h[2] = (f16)v.z; o.h[3] = (f16)v.w;
    *(ushort4*)(zp + (size_t)r * NZ + c) = o.u;
}

// ---------------- transpose W: [g][K][N] f32 -> [g][NPAD][K] f16 ----------------
template<int K, int N, int NPAD>
__global__ __launch_bounds__(256)
void transpose_f16(const float* __restrict__ W, f16* __restrict__ Wt) {
    const int g  = blockIdx.z;
    const int k0 = blockIdx.x * 32;
    const int n0 = blockIdx.y * 32;
    __shared__ f16 L[32][36];
    const int t = threadIdx.x;
    {
        const int kk = t >> 3;
        const int nq = (t & 7) * 4;
        float4 v = make_float4(0.f, 0.f, 0.f, 0.f);
        if (n0 + nq < N)   // N % 4 == 0: quads never straddle
            v = *(const float4*)(W + ((size_t)g * K + (k0 + kk)) * N + n0 + nq);
        L[nq + 0][kk] = (f16)v.x;
        L[nq + 1][kk] = (f16)v.y;
        L[nq + 2][kk] = (f16)v.z;
        L[nq + 3][kk] = (f16)v.w;
    }
    __syncthreads();
    {
        const int nn = t >> 3;
        const int kq = (t & 7) * 4;
        *(ushort4*)(Wt + ((size_t)g * NPAD + (n0 + nn)) * K + k0 + kq) =
            *(const ushort4*)&L[nn][kq];
    }
}

// ---------------- barrier-free weight-stationary grouped GEMM ----------------
// Block = (m-slice, [ksplit x] 32-col n-tile, gen). B-tile [32][KLEN] in LDS
// (KP = KLEN+4: row stride = 2 banks -> frag ds_read_b128 is 2-way = free).
// After one stage barrier, waves stream MFMA A-fragments straight from packed
// global A (contiguous 16 B/lane). Column-permuted B-frags: frag nf holds
// memory col n0 + (lane&15)*2 + nf, so each lane's accs are ADJACENT cols ->
// coalesced ushort2/float2 stores (no line-amplification).
// MODE: 0 = relu -> packed f16 ; 2 = raw f32 partial, packed [ks][row][NOUT].
template<int KLEN, int KSTRIDE, int NOUT, int NPADB, int NTILES,
         int MT, int MSPLIT, int MODE>
__global__ __launch_bounds__(256, 4)
void gemm_ws(const f16* __restrict__ Ap, const f16* __restrict__ Wt,
             const float* __restrict__ bias,
             f16* __restrict__ Ch, float* __restrict__ Cf,
             const int* __restrict__ seg) {
    constexpr int KP = KLEN + 4;
    const int g  = blockIdx.z;
    const int s0 = seg[g], s1 = seg[g + 1];
    const int ng = s1 - s0;
    const int ks   = blockIdx.y / NTILES;
    const int n0   = (blockIdx.y % NTILES) * 32;
    const int koff = ks * KLEN;
    const int m_start = (int)(((long long)blockIdx.x * ng) / MSPLIT);
    const int m_end   = (int)(((long long)(blockIdx.x + 1) * ng) / MSPLIT);
    const int m_len   = m_end - m_start;
    if (m_len <= 0) return;          // block-uniform

    __shared__ f16 Bs[32 * KP];
    const int tid = threadIdx.x;

    #pragma unroll
    for (int i = tid; i < 32 * (KLEN / 8); i += 256) {
        const int row = i / (KLEN / 8);
        const int kq  = (i % (KLEN / 8)) * 8;
        *(half8*)&Bs[row * KP + kq] =
            *(const half8*)(Wt + ((size_t)g * NPADB + n0 + row) * KSTRIDE + koff + kq);
    }
    __syncthreads();

    const int lane = tid & 63, w = tid >> 6;
    const int lm = lane & 15, lq = lane >> 4;

    float bs[2];
    if (MODE == 0) {
        #pragma unroll
        for (int nf = 0; nf < 2; ++nf)
            bs[nf] = bias[(size_t)g * NOUT + n0 + lm * 2 + nf];
    }

    const f16* abase = Ap + koff + lq * 8;

    for (int st = w; st * (MT * 16) < m_len; st += 4) {
        const int mr0 = m_start + st * MT * 16;
        const f16* ap[MT];
        #pragma unroll
        for (int mt = 0; mt < MT; ++mt)
            ap[mt] = abase + (size_t)(s0 + mr0 + mt * 16 + lm) * KSTRIDE;

        floatx4 acc[MT][2] = {};
        #pragma unroll
        for (int kc = 0; kc < KLEN / 32; ++kc) {
            const half8 b0 = *(const half8*)&Bs[(lm * 2 + 0) * KP + kc * 32 + lq * 8];
            const half8 b1 = *(const half8*)&Bs[(lm * 2 + 1) * KP + kc * 32 + lq * 8];
            #pragma unroll
            for (int mt = 0; mt < MT; ++mt) {
                const half8 ah = *(const half8*)(ap[mt] + kc * 32);
                acc[mt][0] = __builtin_amdgcn_mfma_f32_16x16x32_f16(ah, b0, acc[mt][0], 0, 0, 0);
                acc[mt][1] = __builtin_amdgcn_mfma_f32_16x16x32_f16(ah, b1, acc[mt][1], 0, 0, 0);
            }
        }

        // C/D layout: col = lane&15 (-> memory col n0 + lm*2 + nf), row = lq*4+reg
        const int c = n0 + lm * 2;
        #pragma unroll
        for (int mt = 0; mt < MT; ++mt)
            #pragma unroll
            for (int rr = 0; rr < 4; ++rr) {
                const int prow = mr0 + mt * 16 + lq * 4 + rr;
                if (prow >= m_end) continue;
                const size_t row = (size_t)(s0 + prow);
                if (MODE == 0) {
                    union { uint u; f16 h[2]; } o;
                    o.h[0] = (f16)fmaxf(acc[mt][0][rr] + bs[0], 0.f);
                    o.h[1] = (f16)fmaxf(acc[mt][1][rr] + bs[1], 0.f);
                    *(uint*)&Ch[row * NOUT + c] = o.u;
                } else {
                    if (c < NOUT) {   // NOUT even: pair never straddles
                        float2 o = make_float2(acc[mt][0][rr], acc[mt][1][rr]);
                        *(float2*)&Cf[((size_t)ks * BATCH + row) * NOUT + c] = o;
                    }
                }
            }
    }
}

// ---------------- combine K-split partials: tanh(p0+p1+bias), scatter ----------------
__global__ __launch_bounds__(256)
void combine_tanh(const float* __restrict__ p, const float* __restrict__ bias,
                  const int* __restrict__ perm, const int* __restrict__ g_idx,
                  float* __restrict__ out) {
    const int i = blockIdx.x * 256 + threadIdx.x;   // BATCH * (IMG/4)
    const int r  = i / (IMG / 4);
    const int nq = (i % (IMG / 4)) * 4;
    const int s  = perm[r];
    const int g  = g_idx[s];
    float4 a = *(const float4*)(p + (size_t)r * IMG + nq);
    float4 b = *(const float4*)(p + (size_t)BATCH * IMG + (size_t)r * IMG + nq);
    float4 c = *(const float4*)(bias + (size_t)g * IMG + nq);
    float4 rv;
    float* rp = (float*)&rv;
    const float xs[4] = {a.x + b.x + c.x, a.y + b.y + c.y,
                         a.z + b.z + c.z, a.w + b.w + c.w};
    #pragma unroll
    for (int j = 0; j < 4; ++j) {
        const float e = __expf(2.f * xs[j]);     // tanh, inf-safe
        rp[j] = 1.f - 2.f / (e + 1.f);
    }
    *(float4*)(out + (size_t)s * IMG + nq) = rv;
}

extern "C" void kernel_launch(void* const* d_in, const int* in_sizes, int n_in,
                              void* d_out, int out_size, void* d_ws, size_t ws_size,
                              hipStream_t stream) {
    const float* z    = (const float*)d_in[0];
    const int*   gidx = (const int*)  d_in[1];
    const float* W1   = (const float*)d_in[2];
    const float* b1   = (const float*)d_in[3];
    const float* W2   = (const float*)d_in[4];
    const float* b2   = (const float*)d_in[5];
    const float* W3   = (const float*)d_in[6];
    const float* b3   = (const float*)d_in[7];
    float* out = (float*)d_out;

    char* ws = (char*)d_ws;
    size_t off = 0;
    auto alloc = [&](size_t bytes) { size_t o = off; off = (off + bytes + 255) & ~255ULL; return o; };
    int* seg  = (int*)(ws + alloc((size_t)(NGEN + 1) * 4));
    int* perm = (int*)(ws + alloc((size_t)(BATCH + MPAD) * 4));
    f16* zp  = (f16*)(ws + alloc((size_t)(BATCH + MPAD) * NZ * 2));
    f16* h1p = (f16*)(ws + alloc((size_t)(BATCH + MPAD) * H1 * 2));
    f16* h2p = (f16*)(ws + alloc((size_t)(BATCH + MPAD) * H2 * 2));
    f16* W1t = (f16*)(ws + alloc((size_t)NGEN * H1 * NZ * 2));
    f16* W2t = (f16*)(ws + alloc((size_t)NGEN * H2 * H1 * 2));
    f16* W3t = (f16*)(ws + alloc((size_t)NGEN * IMGP * H2 * 2));
    float* p = (float*)(ws + alloc((size_t)2 * BATCH * IMG * 4));

    hist_perm<<<dim3(1), dim3(1024), 0, stream>>>(gidx, seg, perm);
    pack_z<<<dim3(BATCH * (NZ / 4) / 256), dim3(256), 0, stream>>>(z, perm, zp);
    transpose_f16<NZ, H1, H1><<<dim3(NZ / 32, H1 / 32, NGEN), dim3(256), 0, stream>>>(W1, W1t);
    transpose_f16<H1, H2, H2><<<dim3(H1 / 32, H2 / 32, NGEN), dim3(256), 0, stream>>>(W2, W2t);
    transpose_f16<H2, IMG, IMGP><<<dim3(H2 / 32, IMGP / 32, NGEN), dim3(256), 0, stream>>>(W3, W3t);

    // G1: K=128, LDS 8.4 KB, grid (4,16,10)=640; m_len~102 -> 4 supertiles of 32
    gemm_ws<NZ, NZ, H1, H1, H1 / 32, 2, 4, 0>
        <<<dim3(4, H1 / 32, NGEN), dim3(256), 0, stream>>>(
            zp, W1t, b1, h1p, nullptr, seg);
    // G2: K=512, LDS 33 KB (4 blk/CU), grid (4,32,10)=1280; 4 supertiles of 32
    gemm_ws<H1, H1, H2, H2, H2 / 32, 2, 4, 0>
        <<<dim3(4, H2 / 32, NGEN), dim3(256), 0, stream>>>(
            h1p, W2t, b2, h2p, nullptr, seg);
    // G3: K=1024 as 2x512, LDS 33 KB, grid (2,52,10)=1040; m_len~205 -> 4 supertiles of 64
    gemm_ws<512, H2, IMG, IMGP, IMGP / 32, 4, 2, 2>
        <<<dim3(2, 2 * (IMGP / 32), NGEN), dim3(256), 0, stream>>>(
            h2p, W3t, nullptr, nullptr, p, seg);
    // combine: tanh(p0+p1+bias) scattered to out
    combine_tanh<<<dim3(BATCH * (IMG / 4) / 256), dim3(256), 0, stream>>>(
        p, b3, perm, gidx, out);
}

// Round 7
// 181.219 us; speedup vs baseline: 1.8906x; 1.4701x over previous
//
#include <hip/hip_runtime.h>
#include <math.h>

#define NZ    128
#define H1    512
#define H2    1024
#define IMG   784
#define IMGP  832     // layer-3 N padded to 13*64
#define BATCH 4096
#define NGEN  10
#define MPAD  128     // packed-row slack so tail tiles can stage past ng

typedef _Float16 f16;
typedef __attribute__((ext_vector_type(8))) _Float16 half8;
typedef __attribute__((ext_vector_type(4))) float floatx4;

__device__ __forceinline__ void cp16(void* l, const void* g) {
    __builtin_amdgcn_global_load_lds((const __attribute__((address_space(1))) void*)g,
                                     (__attribute__((address_space(3))) void*)l, 16, 0, 0);
}

// ---------------- histogram + segment starts + permutation (one block) ----------------
__global__ __launch_bounds__(1024)
void hist_perm(const int* __restrict__ g_idx, int* __restrict__ seg,
               int* __restrict__ perm) {
    __shared__ int lc[NGEN];
    __shared__ int lb[NGEN + 1];
    const int t = threadIdx.x;
    if (t < NGEN) lc[t] = 0;
    __syncthreads();
    int gv[BATCH / 1024];
    #pragma unroll
    for (int i = 0; i < BATCH / 1024; ++i) {
        gv[i] = g_idx[t + i * 1024];
        atomicAdd(&lc[gv[i]], 1);
    }
    __syncthreads();
    if (t == 0) {
        int s = 0;
        for (int g = 0; g < NGEN; ++g) { lb[g] = s; s += lc[g]; }
        lb[NGEN] = s;
    }
    __syncthreads();
    if (t <= NGEN) seg[t] = lb[t];
    if (t < NGEN) lc[t] = lb[t];          // reuse as cursors
    __syncthreads();
    #pragma unroll
    for (int i = 0; i < BATCH / 1024; ++i) {
        int p = atomicAdd(&lc[gv[i]], 1);
        perm[p] = t + i * 1024;
    }
}

// ---------------- pack + convert z: zp[r][:] = f16(z[perm[r]][:]) ----------------
__global__ void pack_z(const float* __restrict__ z, const int* __restrict__ perm,
                       f16* __restrict__ zp) {
    const int i = blockIdx.x * 256 + threadIdx.x;   // BATCH * (NZ/4)
    const int r = i >> 5, c = (i & 31) * 4;
    const int s = perm[r];
    float4 v = *(const float4*)(z + (size_t)s * NZ + c);
    union { ushort4 u; f16 h[4]; } o;
    o.h[0] = (f16)v.x; o.h[1] = (f16)v.y; o.h[2] = (f16)v.z; o.h[3] = (f16)v.w;
    *(ushort4*)(zp + (size_t)r * NZ + c) = o.u;
}

// ---------------- transpose W: [g][K][N] f32 -> [g][NPAD][K] f16 ----------------
template<int K, int N, int NPAD>
__global__ __launch_bounds__(256)
void transpose_f16(const float* __restrict__ W, f16* __restrict__ Wt) {
    const int g  = blockIdx.z;
    const int k0 = blockIdx.x * 32;
    const int n0 = blockIdx.y * 32;
    __shared__ f16 L[32][36];
    const int t = threadIdx.x;
    {
        const int kk = t >> 3;
        const int nq = (t & 7) * 4;
        float4 v = make_float4(0.f, 0.f, 0.f, 0.f);
        if (n0 + nq < N)   // N % 4 == 0: quads never straddle
            v = *(const float4*)(W + ((size_t)g * K + (k0 + kk)) * N + n0 + nq);
        L[nq + 0][kk] = (f16)v.x;
        L[nq + 1][kk] = (f16)v.y;
        L[nq + 2][kk] = (f16)v.z;
        L[nq + 3][kk] = (f16)v.w;
    }
    __syncthreads();
    {
        const int nn = t >> 3;
        const int kq = (t & 7) * 4;
        *(ushort4*)(Wt + ((size_t)g * NPAD + (n0 + nn)) * K + k0 + kq) =
            *(const ushort4*)&L[nn][kq];
    }
}

// ---------------- 64x64-tile grouped GEMM, m97-style staging ----------------
// Block = (m-tile, n-tile, gen). Single-buffer LDS, global_load_lds width 16.
// LDS layout XOR-swizzled: phys k-quad = logical ^ ((row>>1)&7), so
//   - A-frag reads (16 consecutive rows)   -> 2-way bank conflict (free)
//   - B-frag reads (stride-2 rows, col-permuted) -> 2-way (free)
// Column-permuted B: frag nf holds memory col n0+wn+2*lm+nf -> each lane's
// accumulators are adjacent columns -> ushort2/float2 coalesced stores.
// 4 waves in 2x2 (32x32 each): per BK=64 iter, 8 ds_read_b128 + 8 MFMA/wave.
// ACT: 0 relu, 1 tanh. SCATTER: 0 -> packed f16 Ch; 1 -> f32 out via perm.
template<int K, int NOUT, int NPADB, int ACT, int SCATTER>
__global__ __launch_bounds__(256)
void gemm64(const f16* __restrict__ Ap, const f16* __restrict__ Wt,
            const float* __restrict__ bias, f16* __restrict__ Ch,
            float* __restrict__ Cout, const int* __restrict__ seg,
            const int* __restrict__ perm) {
    const int g  = blockIdx.z;
    const int s0 = seg[g];
    const int ng = seg[g + 1] - s0;
    const int m0 = blockIdx.x * 64;
    if (m0 >= ng) return;                 // block-uniform early exit
    const int n0 = blockIdx.y * 64;

    __shared__ f16 As[64 * 64];
    __shared__ f16 Bs[64 * 64];

    const int tid = threadIdx.x, lane = tid & 63, w = tid >> 6;

    // staging: wave w stages rows [w*16, w*16+16) of both tiles, 2 cp16 each.
    // cp16 dest = wave-uniform base + lane*16 -> row = base_row + (lane>>3),
    // phys quad = lane&7; fetch global logical quad (lane&7) ^ ((row>>1)&7).
    const f16* ga[2]; const f16* gb[2]; f16* la[2]; f16* lb[2];
    #pragma unroll
    for (int j = 0; j < 2; ++j) {
        const int r   = w * 16 + j * 8 + (lane >> 3);
        const int swz = ((lane & 7) ^ ((r >> 1) & 7)) * 8;
        ga[j] = Ap + (size_t)(s0 + m0 + r) * K + swz;
        gb[j] = Wt + ((size_t)g * NPADB + n0 + r) * K + swz;
        la[j] = As + (w * 16 + j * 8) * 64;
        lb[j] = Bs + (w * 16 + j * 8) * 64;
    }

    const int wm = (w & 1) * 32, wn = (w >> 1) * 32;
    const int lm = lane & 15, lq = lane >> 4;

    floatx4 acc[2][2] = {};

    #pragma unroll
    for (int kc = 0; kc < K / 64; ++kc) {
        __syncthreads();                  // prior frag reads done: LDS reusable
        #pragma unroll
        for (int j = 0; j < 2; ++j) {
            cp16(la[j], ga[j]); cp16(lb[j], gb[j]);
            ga[j] += 64; gb[j] += 64;
        }
        __syncthreads();                  // staging drained (vmcnt before barrier)
        #pragma unroll
        for (int ks = 0; ks < 2; ++ks) {
            half8 a[2], b[2];
            #pragma unroll
            for (int mt = 0; mt < 2; ++mt) {
                const int r  = wm + mt * 16 + lm;
                const int pq = (ks * 4 + lq) ^ ((r >> 1) & 7);
                a[mt] = *(const half8*)&As[r * 64 + pq * 8];
            }
            #pragma unroll
            for (int nf = 0; nf < 2; ++nf) {
                const int r  = wn + 2 * lm + nf;
                const int pq = (ks * 4 + lq) ^ ((r >> 1) & 7);
                b[nf] = *(const half8*)&Bs[r * 64 + pq * 8];
            }
            #pragma unroll
            for (int mt = 0; mt < 2; ++mt)
                #pragma unroll
                for (int nf = 0; nf < 2; ++nf)
                    acc[mt][nf] = __builtin_amdgcn_mfma_f32_16x16x32_f16(
                        a[mt], b[nf], acc[mt][nf], 0, 0, 0);
        }
    }

    // epilogue: C/D layout col = lane&15 (-> memory col n0+wn+2*lm+nf),
    // row = (lane>>4)*4 + reg. Paired columns -> 2-elem vector stores.
    const int c = n0 + wn + 2 * lm;
    const float b0 = (c     < NOUT) ? bias[(size_t)g * NOUT + c]     : 0.f;
    const float b1 = (c + 1 < NOUT) ? bias[(size_t)g * NOUT + c + 1] : 0.f;
    #pragma unroll
    for (int mt = 0; mt < 2; ++mt)
        #pragma unroll
        for (int rr = 0; rr < 4; ++rr) {
            const int gr = m0 + wm + mt * 16 + lq * 4 + rr;
            if (gr >= ng) continue;
            float x0 = acc[mt][0][rr] + b0;
            float x1 = acc[mt][1][rr] + b1;
            if (ACT == 0) {
                x0 = fmaxf(x0, 0.f); x1 = fmaxf(x1, 0.f);
            } else {                       // tanh, inf-safe
                const float e0 = __expf(2.f * x0);
                const float e1 = __expf(2.f * x1);
                x0 = 1.f - 2.f / (e0 + 1.f);
                x1 = 1.f - 2.f / (e1 + 1.f);
            }
            if (SCATTER) {
                if (c < NOUT) {            // NOUT even: pair never straddles
                    const size_t orow = (size_t)perm[s0 + gr];
                    *(float2*)&Cout[orow * NOUT + c] = make_float2(x0, x1);
                }
            } else {
                union { uint u; f16 h[2]; } o;
                o.h[0] = (f16)x0; o.h[1] = (f16)x1;
                *(uint*)&Ch[(size_t)(s0 + gr) * NOUT + c] = o.u;
            }
        }
}

extern "C" void kernel_launch(void* const* d_in, const int* in_sizes, int n_in,
                              void* d_out, int out_size, void* d_ws, size_t ws_size,
                              hipStream_t stream) {
    const float* z    = (const float*)d_in[0];
    const int*   gidx = (const int*)  d_in[1];
    const float* W1   = (const float*)d_in[2];
    const float* b1   = (const float*)d_in[3];
    const float* W2   = (const float*)d_in[4];
    const float* b2   = (const float*)d_in[5];
    const float* W3   = (const float*)d_in[6];
    const float* b3   = (const float*)d_in[7];
    float* out = (float*)d_out;

    char* ws = (char*)d_ws;
    size_t off = 0;
    auto alloc = [&](size_t bytes) { size_t o = off; off = (off + bytes + 255) & ~255ULL; return o; };
    int* seg  = (int*)(ws + alloc((size_t)(NGEN + 1) * 4));
    int* perm = (int*)(ws + alloc((size_t)(BATCH + MPAD) * 4));
    f16* zp  = (f16*)(ws + alloc((size_t)(BATCH + MPAD) * NZ * 2));
    f16* h1p = (f16*)(ws + alloc((size_t)(BATCH + MPAD) * H1 * 2));
    f16* h2p = (f16*)(ws + alloc((size_t)(BATCH + MPAD) * H2 * 2));
    f16* W1t = (f16*)(ws + alloc((size_t)NGEN * H1 * NZ * 2));
    f16* W2t = (f16*)(ws + alloc((size_t)NGEN * H2 * H1 * 2));
    f16* W3t = (f16*)(ws + alloc((size_t)NGEN * IMGP * H2 * 2));

    hist_perm<<<dim3(1), dim3(1024), 0, stream>>>(gidx, seg, perm);
    pack_z<<<dim3(BATCH * (NZ / 4) / 256), dim3(256), 0, stream>>>(z, perm, zp);
    transpose_f16<NZ, H1, H1><<<dim3(NZ / 32, H1 / 32, NGEN), dim3(256), 0, stream>>>(W1, W1t);
    transpose_f16<H1, H2, H2><<<dim3(H1 / 32, H2 / 32, NGEN), dim3(256), 0, stream>>>(W2, W2t);
    transpose_f16<H2, IMG, IMGP><<<dim3(H2 / 32, IMGP / 32, NGEN), dim3(256), 0, stream>>>(W3, W3t);

    // grid.x = 16 covers any plausible bucket size (<=1024); empty m-tiles
    // exit on the seg[] read. Active blocks: ~7 m-tiles/gen (ng ~ 410).
    gemm64<NZ, H1, H1, 0, 0><<<dim3(16, H1 / 64, NGEN), dim3(256), 0, stream>>>(
        zp, W1t, b1, h1p, nullptr, seg, perm);
    gemm64<H1, H2, H2, 0, 0><<<dim3(16, H2 / 64, NGEN), dim3(256), 0, stream>>>(
        h1p, W2t, b2, h2p, nullptr, seg, perm);
    gemm64<H2, IMG, IMGP, 1, 1><<<dim3(16, IMGP / 64, NGEN), dim3(256), 0, stream>>>(
        h2p, W3t, b3, nullptr, out, seg, perm);
}